// Round 12
// baseline (1865.326 us; speedup 1.0000x reference)
//
#include <hip/hip_runtime.h>
#include <hip/hip_fp16.h>
#include <stdint.h>

#define N_NODES   100000
#define N_EDGES   3200000
#define F_IN      128
#define F_HID     64
#define F_OUT     16

typedef _Float16 h2v __attribute__((ext_vector_type(2)));

// bucket partition params
#define BSHIFT    8
#define NBUCK     391                  // ceil(100000 / 256)
#define NBLK_P    512                  // partition blocks
#define CHUNK_E   (N_EDGES / NBLK_P)   // 6250 edges per block
#define PSTRIDE   9472                 // bucket region capacity (mean 8184 + ~14 sigma)

// gemm1 tiling
#define G1_TM     128
#define G1_BLOCKS ((N_NODES + G1_TM - 1) / G1_TM)   // 782
#define XS_LD     132

// ---- workspace layout (bytes), 16B-aligned ----
#define OFF_DINV     0                 // float[N]
#define OFF_GCNT     400000            // int[NBUCK]
#define OFF_FLAG     401568            // int   1 => edge_index is int64
#define OFF_PAIRS    401584            // uint[NBUCK*PSTRIDE] = 14,814,208 B
#define OFF_HS1      15215792          // half[2][N_NODES][32] (32-feat chunk-major)
#define OFF_OUT1     28015792          // float[N*64] = 25.6 MB
#define OFF_HS2      53615792          // half[N_NODES*16]
// total 56,815,792 bytes

__device__ __forceinline__ int edge_src(const void* ei, int is64, int e) {
    return is64 ? (int)((const long long*)ei)[e] : ((const int*)ei)[e];
}
__device__ __forceinline__ int edge_dst(const void* ei, int is64, int e) {
    return is64 ? (int)((const long long*)ei)[N_EDGES + e]
                : ((const int*)ei)[N_EDGES + e];
}

// ---- init: zero gcnt + one-time dtype detect -------------------------------
__global__ void k_init(const void* __restrict__ ei, int* __restrict__ gcnt,
                       int* __restrict__ flag) {
    int t = threadIdx.x;
    for (int i = t; i < NBUCK; i += 512) gcnt[i] = 0;
    if (t == 0) {
        // int64 data viewed as u32 pairs: [lo<100000, hi==0] x 64. For int32
        // data the hi words are random node ids: P(all zero) ~ 0.
        const unsigned* u = (const unsigned*)ei;
        int ok = 1;
        for (int i = 0; i < 64; ++i) {
            unsigned lo = u[2 * i], hi = u[2 * i + 1];
            if (hi != 0u || lo >= 100000u) { ok = 0; break; }
        }
        *flag = ok;
    }
}

// ---- pass 1: partition edges into fixed-capacity bucket regions ------------
__global__ __launch_bounds__(256) void k_partition(const void* __restrict__ ei,
                                                   const int* __restrict__ flag,
                                                   int* __restrict__ gcnt,
                                                   unsigned* __restrict__ pairs) {
    __shared__ int h[NBUCK];
    __shared__ int cur[NBUCK];
    int t = threadIdx.x;
    for (int i = t; i < NBUCK; i += 256) h[i] = 0;
    __syncthreads();
    int is64 = *flag;
    int base = blockIdx.x * CHUNK_E;
    for (int i = t; i < CHUNK_E; i += 256)
        atomicAdd(&h[edge_dst(ei, is64, base + i) >> BSHIFT], 1);
    __syncthreads();
    for (int i = t; i < NBUCK; i += 256) {
        int c = h[i];
        cur[i] = c ? atomicAdd(&gcnt[i], c) : 0;
    }
    __syncthreads();
    for (int i = t; i < CHUNK_E; i += 256) {
        int e = base + i;
        int s = edge_src(ei, is64, e);
        int d = edge_dst(ei, is64, e);
        int b = d >> BSHIFT;
        int p = atomicAdd(&cur[b], 1);
        if (p < PSTRIDE)   // statistically impossible to overflow; guard anyway
            pairs[b * PSTRIDE + p] = ((unsigned)s << 8) | (unsigned)(d & 255);
    }
}

// ---- pass 2: per-bucket degree count -> dinv (no CSR needed anymore) -------
__global__ __launch_bounds__(512) void k_dcount(const unsigned* __restrict__ pairs,
                                                const int* __restrict__ gcnt,
                                                float* __restrict__ dinv) {
    __shared__ int c[256];
    int b = blockIdx.x, t = threadIdx.x;
    if (t < 256) c[t] = 0;
    __syncthreads();
    int tot = gcnt[b]; if (tot > PSTRIDE) tot = PSTRIDE;
    int base = b * PSTRIDE;
    for (int i = t; i < tot; i += 512)
        atomicAdd(&c[pairs[base + i] & 255u], 1);
    __syncthreads();
    if (t < 256) {
        int d = (b << BSHIFT) + t;
        if (d < N_NODES) dinv[d] = rsqrtf((float)c[t] + 1.0f);
    }
}

// ---- GEMM1 (LDS-tiled): hs1[chunk32][node][32] = (x@W1)*dinv ---------------
__global__ __launch_bounds__(256) void k_gemm1(const float* __restrict__ x,
                                               const float* __restrict__ W1,
                                               const float* __restrict__ dinv,
                                               __half* __restrict__ hs1) {
    __shared__ float xsT[64 * XS_LD];
    __shared__ float ws[64 * 64];
    int t = threadIdx.x;
    int nblock = blockIdx.x * G1_TM;
    int ng = t >> 4, og = t & 15;
    int n0 = ng * 8;
    float acc[8][4] = {};

    int snode = nblock + (t >> 1);
    int koff = (t & 1) * 32;
    int nl = t >> 1;

    for (int chunk = 0; chunk < 2; ++chunk) {
        int kbase = chunk * 64;
        {
            float4 v[8];
            if (snode < N_NODES) {
                const float4* src = (const float4*)(x + (size_t)snode * F_IN + kbase + koff);
#pragma unroll
                for (int c = 0; c < 8; ++c) v[c] = src[c];
            } else {
#pragma unroll
                for (int c = 0; c < 8; ++c) v[c] = make_float4(0.f, 0.f, 0.f, 0.f);
            }
#pragma unroll
            for (int c = 0; c < 8; ++c) {
                int k = koff + c * 4;
                xsT[(k + 0) * XS_LD + nl] = v[c].x;
                xsT[(k + 1) * XS_LD + nl] = v[c].y;
                xsT[(k + 2) * XS_LD + nl] = v[c].z;
                xsT[(k + 3) * XS_LD + nl] = v[c].w;
            }
        }
        {
            const float4* wsrc = (const float4*)(W1 + kbase * F_HID);
            float4* wdst = (float4*)ws;
#pragma unroll
            for (int c = 0; c < 4; ++c) wdst[c * 256 + t] = wsrc[c * 256 + t];
        }
        __syncthreads();

#pragma unroll 4
        for (int k = 0; k < 64; ++k) {
            const float4* xr = (const float4*)(xsT + k * XS_LD + n0);
            float4 a0 = xr[0], a1 = xr[1];
            float4 bv = *(const float4*)(ws + k * 64 + og * 4);
            float a[8] = {a0.x, a0.y, a0.z, a0.w, a1.x, a1.y, a1.z, a1.w};
            float bb[4] = {bv.x, bv.y, bv.z, bv.w};
#pragma unroll
            for (int i = 0; i < 8; ++i)
#pragma unroll
                for (int j = 0; j < 4; ++j)
                    acc[i][j] += a[i] * bb[j];
        }
        __syncthreads();
    }

    // epilogue: 32-feat chunk-major hs1[(og>>3)*N + node][32] + (og&7)*4
#pragma unroll
    for (int i = 0; i < 8; ++i) {
        int node = nblock + n0 + i;
        if (node < N_NODES) {
            float dv = dinv[node];
            union { __half2 h[2]; float2 f; } u;
            u.h[0] = __floats2half2_rn(acc[i][0] * dv, acc[i][1] * dv);
            u.h[1] = __floats2half2_rn(acc[i][2] * dv, acc[i][3] * dv);
            *(float2*)(hs1 + ((size_t)(og >> 3) * N_NODES + node) * 32 + (og & 7) * 4) = u.f;
        }
    }
}

// ---- aggregate layer 1: LDS scatter-accumulate, 2 XCD-pinned chunk passes --
// block = (bucket, chunk); LDS fp32 acc[256][33] (pad 33: bank=(dloc+2f)%32).
// Stream bucket's pairs: 16 featpair-lanes per edge, one 4B gather + two
// fire-and-forget ds_add_f32 per lane. No CSR, no padding, no row loop.
__global__ __launch_bounds__(256) void k_agg1(const __half* __restrict__ hs1,
                                              const unsigned* __restrict__ pairs,
                                              const int* __restrict__ gcnt,
                                              const float* __restrict__ dinv,
                                              const float* __restrict__ b1,
                                              float* __restrict__ out1) {
    __shared__ float acc[256 * 33];
    int bid = blockIdx.x;            // grid = 2*NBUCK
    int chunk = bid & 1;             // chunk 0 -> even XCDs, 1 -> odd
    int b = bid >> 1;
    int t = threadIdx.x;
    for (int i = t; i < 256 * 33; i += 256) acc[i] = 0.f;
    __syncthreads();
    int w = t >> 6, lane = t & 63;
    int eslot = lane >> 4, fp = lane & 15;
    const char* T = (const char*)(hs1 + (size_t)chunk * ((size_t)N_NODES * 32));
    unsigned fo = fp * 4u;
    int tot = gcnt[b]; if (tot > PSTRIDE) tot = PSTRIDE;
    const unsigned* P = pairs + b * PSTRIDE;
    int i = w * 4 + eslot;
    for (; i + 16 < tot; i += 32) {
        unsigned p0 = P[i], p1 = P[i + 16];
        h2v v0 = *(const h2v*)(T + ((p0 >> 8) * 64u + fo));
        h2v v1 = *(const h2v*)(T + ((p1 >> 8) * 64u + fo));
        float* a0 = &acc[(p0 & 255u) * 33 + fp * 2];
        atomicAdd(a0,     (float)v0.x);
        atomicAdd(a0 + 1, (float)v0.y);
        float* a1 = &acc[(p1 & 255u) * 33 + fp * 2];
        atomicAdd(a1,     (float)v1.x);
        atomicAdd(a1 + 1, (float)v1.y);
    }
    if (i < tot) {
        unsigned p0 = P[i];
        h2v v0 = *(const h2v*)(T + ((p0 >> 8) * 64u + fo));
        float* a0 = &acc[(p0 & 255u) * 33 + fp * 2];
        atomicAdd(a0,     (float)v0.x);
        atomicAdd(a0 + 1, (float)v0.y);
    }
    __syncthreads();
    // epilogue: thread t owns node d; self + dinv + bias + relu, float4 stores
    int d = (b << BSHIFT) + t;
    if (d < N_NODES) {
        float dv = dinv[d];
        const h2v* S = (const h2v*)(T + (unsigned)d * 64u);
        const float* ap = &acc[t * 33];
        float4* dst = (float4*)(out1 + (size_t)d * F_HID + chunk * 32);
        const float* bb = b1 + chunk * 32;
#pragma unroll
        for (int f8 = 0; f8 < 8; ++f8) {
            h2v s0 = S[f8 * 2], s1 = S[f8 * 2 + 1];
            float4 r;
            r.x = fmaxf(dv * (ap[f8 * 4 + 0] + (float)s0.x) + bb[f8 * 4 + 0], 0.f);
            r.y = fmaxf(dv * (ap[f8 * 4 + 1] + (float)s0.y) + bb[f8 * 4 + 1], 0.f);
            r.z = fmaxf(dv * (ap[f8 * 4 + 2] + (float)s1.x) + bb[f8 * 4 + 2], 0.f);
            r.w = fmaxf(dv * (ap[f8 * 4 + 3] + (float)s1.y) + bb[f8 * 4 + 3], 0.f);
            dst[f8] = r;
        }
    }
}

// ---- GEMM2: hs2 = (out1 @ W2) * dinv, fp16, W2 in LDS ----------------------
__global__ __launch_bounds__(256) void k_gemm2(const float* __restrict__ h,
                                               const float* __restrict__ W2,
                                               const float* __restrict__ dinv,
                                               __half* __restrict__ hs2) {
    __shared__ float ws[F_HID * F_OUT];
    int t = threadIdx.x;
    ((float4*)ws)[t] = ((const float4*)W2)[t];
    __syncthreads();
    int tid = blockIdx.x * 256 + t;
    int n = tid >> 2;
    if (n >= N_NODES) return;
    int cq = (tid & 3) << 2;
    const float4* h4 = (const float4*)(h + (size_t)n * F_HID);
    float4 acc = make_float4(0.f, 0.f, 0.f, 0.f);
#pragma unroll 4
    for (int k4 = 0; k4 < 16; ++k4) {
        float4 hv = h4[k4];
        float4 w0 = *(const float4*)(ws + (k4 * 4 + 0) * F_OUT + cq);
        float4 w1 = *(const float4*)(ws + (k4 * 4 + 1) * F_OUT + cq);
        float4 w2 = *(const float4*)(ws + (k4 * 4 + 2) * F_OUT + cq);
        float4 w3 = *(const float4*)(ws + (k4 * 4 + 3) * F_OUT + cq);
        acc.x += hv.x * w0.x + hv.y * w1.x + hv.z * w2.x + hv.w * w3.x;
        acc.y += hv.x * w0.y + hv.y * w1.y + hv.z * w2.y + hv.w * w3.y;
        acc.z += hv.x * w0.z + hv.y * w1.z + hv.z * w2.z + hv.w * w3.z;
        acc.w += hv.x * w0.w + hv.y * w1.w + hv.z * w2.w + hv.w * w3.w;
    }
    float dv = dinv[n];
    union { __half2 h2[2]; float2 f; } u;
    u.h2[0] = __floats2half2_rn(acc.x * dv, acc.y * dv);
    u.h2[1] = __floats2half2_rn(acc.z * dv, acc.w * dv);
    *(float2*)(hs2 + (size_t)n * F_OUT + cq) = u.f;
}

// ---- aggregate layer 2: LDS scatter-accumulate, single pass ----------------
// Table 3.2MB L2-resident. 8 featpair-lanes per edge, 8 edges per wave-iter.
__global__ __launch_bounds__(256) void k_agg2(const __half* __restrict__ hs2,
                                              const unsigned* __restrict__ pairs,
                                              const int* __restrict__ gcnt,
                                              const float* __restrict__ dinv,
                                              const float* __restrict__ b2,
                                              float* __restrict__ out) {
    __shared__ float acc[256 * 17];
    int b = blockIdx.x;              // grid = NBUCK
    int t = threadIdx.x;
    for (int i = t; i < 256 * 17; i += 256) acc[i] = 0.f;
    __syncthreads();
    int w = t >> 6, lane = t & 63;
    int eslot = lane >> 3, fp = lane & 7;
    const char* T = (const char*)hs2;
    unsigned fo = fp * 4u;
    int tot = gcnt[b]; if (tot > PSTRIDE) tot = PSTRIDE;
    const unsigned* P = pairs + b * PSTRIDE;
    int i = w * 8 + eslot;
    for (; i + 32 < tot; i += 64) {
        unsigned p0 = P[i], p1 = P[i + 32];
        h2v v0 = *(const h2v*)(T + ((p0 >> 8) * 32u + fo));
        h2v v1 = *(const h2v*)(T + ((p1 >> 8) * 32u + fo));
        float* a0 = &acc[(p0 & 255u) * 17 + fp * 2];
        atomicAdd(a0,     (float)v0.x);
        atomicAdd(a0 + 1, (float)v0.y);
        float* a1 = &acc[(p1 & 255u) * 17 + fp * 2];
        atomicAdd(a1,     (float)v1.x);
        atomicAdd(a1 + 1, (float)v1.y);
    }
    if (i < tot) {
        unsigned p0 = P[i];
        h2v v0 = *(const h2v*)(T + ((p0 >> 8) * 32u + fo));
        float* a0 = &acc[(p0 & 255u) * 17 + fp * 2];
        atomicAdd(a0,     (float)v0.x);
        atomicAdd(a0 + 1, (float)v0.y);
    }
    __syncthreads();
    int d = (b << BSHIFT) + t;
    if (d < N_NODES) {
        float dv = dinv[d];
        const h2v* S = (const h2v*)(T + (unsigned)d * 32u);
        const float* ap = &acc[t * 17];
        float4* dst = (float4*)(out + (size_t)d * F_OUT);
#pragma unroll
        for (int f8 = 0; f8 < 4; ++f8) {
            h2v s0 = S[f8 * 2], s1 = S[f8 * 2 + 1];
            float4 r;
            r.x = dv * (ap[f8 * 4 + 0] + (float)s0.x) + b2[f8 * 4 + 0];
            r.y = dv * (ap[f8 * 4 + 1] + (float)s0.y) + b2[f8 * 4 + 1];
            r.z = dv * (ap[f8 * 4 + 2] + (float)s1.x) + b2[f8 * 4 + 2];
            r.w = dv * (ap[f8 * 4 + 3] + (float)s1.y) + b2[f8 * 4 + 3];
            dst[f8] = r;
        }
    }
}

extern "C" void kernel_launch(void* const* d_in, const int* in_sizes, int n_in,
                              void* d_out, int out_size, void* d_ws, size_t ws_size,
                              hipStream_t stream) {
    const float* x  = (const float*)d_in[0];
    const void*  ei = d_in[1];
    const float* W1 = (const float*)d_in[2];
    const float* b1 = (const float*)d_in[3];
    const float* W2 = (const float*)d_in[4];
    const float* b2 = (const float*)d_in[5];
    float* out = (float*)d_out;

    char* ws = (char*)d_ws;
    float*    dinv  = (float*)(ws + OFF_DINV);
    int*      gcnt  = (int*)(ws + OFF_GCNT);
    int*      flag  = (int*)(ws + OFF_FLAG);
    unsigned* pairs = (unsigned*)(ws + OFF_PAIRS);
    __half*   hs1   = (__half*)(ws + OFF_HS1);
    float*    out1  = (float*)(ws + OFF_OUT1);
    __half*   hs2   = (__half*)(ws + OFF_HS2);

    // edge prep: init + bucket partition + degree/dinv (no CSR build)
    k_init     <<<1, 512, 0, stream>>>(ei, gcnt, flag);
    k_partition<<<NBLK_P, 256, 0, stream>>>(ei, flag, gcnt, pairs);
    k_dcount   <<<NBUCK, 512, 0, stream>>>(pairs, gcnt, dinv);

    // GCN layers
    k_gemm1<<<G1_BLOCKS, 256, 0, stream>>>(x, W1, dinv, hs1);
    k_agg1 <<<2 * NBUCK, 256, 0, stream>>>(hs1, pairs, gcnt, dinv, b1, out1);
    k_gemm2<<<(N_NODES * 4 + 255) / 256, 256, 0, stream>>>(out1, W2, dinv, hs2);
    k_agg2 <<<NBUCK, 256, 0, stream>>>(hs2, pairs, gcnt, dinv, b2, out);
}

// Round 13
// 309.800 us; speedup vs baseline: 6.0211x; 6.0211x over previous
//
#include <hip/hip_runtime.h>
#include <hip/hip_fp16.h>
#include <stdint.h>

#define N_NODES   100000
#define N_HALF    50000
#define N_EDGES   3200000
#define F_IN      128
#define F_HID     64
#define F_OUT     16

typedef _Float16 h2v __attribute__((ext_vector_type(2)));

// bucket partition params
#define BSHIFT    8
#define NBUCK     391                  // ceil(100000 / 256)
#define NBLK_P    512                  // partition blocks
#define CHUNK_E   (N_EDGES / NBLK_P)   // 6250 edges per block
#define PSTRIDE   9856                 // bucket capacity: mean 8192 + align-gaps ~850 + ~9 sigma

// gemm1 tiling
#define G1_TM     128
#define G1_BLOCKS ((N_NODES + G1_TM - 1) / G1_TM)   // 782
#define XS_LD     132

// ---- workspace layout (bytes), 16B-aligned ----
#define OFF_RS       0                 // int[N]   rowstart (csr entry index, mult of 4)
#define OFF_LEN      400000            // int[N]   c0 | c1<<16 (raw counts per src-half)
#define OFF_DINV     800000            // float[N]
#define OFF_GCNT     1200000           // int[NBUCK]
#define OFF_FLAG     1201600           // int   1 => edge_index is int64
#define OFF_CSR      1201616           // u16[NBUCK*PSTRIDE] = 7,707,392 B (half-local src)
#define OFF_HS1      8909008           // half[2][N][32] = 12,800,000 B
#define OFF_OUT1A    21709008          // half[N][64] partials (src<50k)
#define OFF_OUT1B    34509008          // half[N][64] partials (src>=50k)
#define OFF_HS2      47309008          // half[N][16]
#define OFF_PAIRS    OFF_OUT1A         // uint[NBUCK*PSTRIDE] = 15.4 MB, aliases out1a/b
// total 50,509,008 bytes

__device__ __forceinline__ int edge_src(const void* ei, int is64, int e) {
    return is64 ? (int)((const long long*)ei)[e] : ((const int*)ei)[e];
}
__device__ __forceinline__ int edge_dst(const void* ei, int is64, int e) {
    return is64 ? (int)((const long long*)ei)[N_EDGES + e]
                : ((const int*)ei)[N_EDGES + e];
}

// ---- init: zero gcnt + one-time dtype detect -------------------------------
__global__ void k_init(const void* __restrict__ ei, int* __restrict__ gcnt,
                       int* __restrict__ flag) {
    int t = threadIdx.x;
    for (int i = t; i < NBUCK; i += 512) gcnt[i] = 0;
    if (t == 0) {
        // int64 data viewed as u32 pairs: [lo<100000, hi==0] x 64. For int32
        // data the hi words are random node ids: P(all zero) ~ 0.
        const unsigned* u = (const unsigned*)ei;
        int ok = 1;
        for (int i = 0; i < 64; ++i) {
            unsigned lo = u[2 * i], hi = u[2 * i + 1];
            if (hi != 0u || lo >= 100000u) { ok = 0; break; }
        }
        *flag = ok;
    }
}

// ---- pass 1: partition edges into fixed-capacity bucket regions ------------
__global__ __launch_bounds__(256) void k_partition(const void* __restrict__ ei,
                                                   const int* __restrict__ flag,
                                                   int* __restrict__ gcnt,
                                                   unsigned* __restrict__ pairs) {
    __shared__ int h[NBUCK];
    __shared__ int cur[NBUCK];
    int t = threadIdx.x;
    for (int i = t; i < NBUCK; i += 256) h[i] = 0;
    __syncthreads();
    int is64 = *flag;
    int base = blockIdx.x * CHUNK_E;
    for (int i = t; i < CHUNK_E; i += 256)
        atomicAdd(&h[edge_dst(ei, is64, base + i) >> BSHIFT], 1);
    __syncthreads();
    for (int i = t; i < NBUCK; i += 256) {
        int c = h[i];
        cur[i] = c ? atomicAdd(&gcnt[i], c) : 0;
    }
    __syncthreads();
    for (int i = t; i < CHUNK_E; i += 256) {
        int e = base + i;
        int s = edge_src(ei, is64, e);
        int d = edge_dst(ei, is64, e);
        int b = d >> BSHIFT;
        int p = atomicAdd(&cur[b], 1);
        if (p < PSTRIDE)   // statistically impossible to overflow; guard anyway
            pairs[b * PSTRIDE + p] = ((unsigned)s << 8) | (unsigned)(d & 255);
    }
}

// ---- pass 2: per-bucket count/scan/place, split by src-half ----------------
// Per node: sub-row 0 (src<50000) then sub-row 1, each start 4-entry aligned.
// Entries are u16 half-local src. No padding writes (raw counts stored).
__global__ __launch_bounds__(512) void k_build(const unsigned* __restrict__ pairs,
                                               const int* __restrict__ gcnt,
                                               int* __restrict__ rowstart,
                                               int* __restrict__ lens,
                                               float* __restrict__ dinv,
                                               unsigned short* __restrict__ csr) {
    __shared__ int c0S[256], c1S[256], scanS[256], pos0[256], pos1[256];
    int b = blockIdx.x, t = threadIdx.x;
    if (t < 256) { c0S[t] = 0; c1S[t] = 0; }
    __syncthreads();
    int tot = gcnt[b]; if (tot > PSTRIDE) tot = PSTRIDE;
    int base = b * PSTRIDE;
    for (int i = t; i < tot; i += 512) {
        unsigned pr = pairs[base + i];
        if ((pr >> 8) < (unsigned)N_HALF) atomicAdd(&c0S[pr & 255u], 1);
        else                              atomicAdd(&c1S[pr & 255u], 1);
    }
    __syncthreads();
    int tpad = 0, p0a = 0;
    if (t < 256) {
        p0a = (c0S[t] + 3) & ~3;
        tpad = p0a + ((c1S[t] + 3) & ~3);
        scanS[t] = tpad;
    }
    __syncthreads();
    for (int off = 1; off < 256; off <<= 1) {
        int add = 0;
        if (t < 256 && t >= off) add = scanS[t - off];
        __syncthreads();
        if (t < 256) scanS[t] += add;
        __syncthreads();
    }
    if (t < 256) {
        int rs = base + scanS[t] - tpad;   // exclusive scan, 4-entry aligned
        pos0[t] = rs;
        pos1[t] = rs + p0a;
        int d = (b << BSHIFT) + t;
        if (d < N_NODES) {
            rowstart[d] = rs;
            lens[d] = c0S[t] | (c1S[t] << 16);
            dinv[d] = rsqrtf((float)(c0S[t] + c1S[t]) + 1.0f);
        }
    }
    __syncthreads();
    for (int i = t; i < tot; i += 512) {
        unsigned pr = pairs[base + i];
        unsigned s = pr >> 8;
        int d = pr & 255u;
        if (s < (unsigned)N_HALF) {
            int p = atomicAdd(&pos0[d], 1);
            csr[p] = (unsigned short)s;
        } else {
            int p = atomicAdd(&pos1[d], 1);
            csr[p] = (unsigned short)(s - N_HALF);
        }
    }
}

// ---- GEMM1 (LDS-tiled): hs1[chunk32][node][32] = (x@W1)*dinv ---------------
__global__ __launch_bounds__(256) void k_gemm1(const float* __restrict__ x,
                                               const float* __restrict__ W1,
                                               const float* __restrict__ dinv,
                                               __half* __restrict__ hs1) {
    __shared__ float xsT[64 * XS_LD];
    __shared__ float ws[64 * 64];
    int t = threadIdx.x;
    int nblock = blockIdx.x * G1_TM;
    int ng = t >> 4, og = t & 15;
    int n0 = ng * 8;
    float acc[8][4] = {};

    int snode = nblock + (t >> 1);
    int koff = (t & 1) * 32;
    int nl = t >> 1;

    for (int chunk = 0; chunk < 2; ++chunk) {
        int kbase = chunk * 64;
        {
            float4 v[8];
            if (snode < N_NODES) {
                const float4* src = (const float4*)(x + (size_t)snode * F_IN + kbase + koff);
#pragma unroll
                for (int c = 0; c < 8; ++c) v[c] = src[c];
            } else {
#pragma unroll
                for (int c = 0; c < 8; ++c) v[c] = make_float4(0.f, 0.f, 0.f, 0.f);
            }
#pragma unroll
            for (int c = 0; c < 8; ++c) {
                int k = koff + c * 4;
                xsT[(k + 0) * XS_LD + nl] = v[c].x;
                xsT[(k + 1) * XS_LD + nl] = v[c].y;
                xsT[(k + 2) * XS_LD + nl] = v[c].z;
                xsT[(k + 3) * XS_LD + nl] = v[c].w;
            }
        }
        {
            const float4* wsrc = (const float4*)(W1 + kbase * F_HID);
            float4* wdst = (float4*)ws;
#pragma unroll
            for (int c = 0; c < 4; ++c) wdst[c * 256 + t] = wsrc[c * 256 + t];
        }
        __syncthreads();

#pragma unroll 4
        for (int k = 0; k < 64; ++k) {
            const float4* xr = (const float4*)(xsT + k * XS_LD + n0);
            float4 a0 = xr[0], a1 = xr[1];
            float4 bv = *(const float4*)(ws + k * 64 + og * 4);
            float a[8] = {a0.x, a0.y, a0.z, a0.w, a1.x, a1.y, a1.z, a1.w};
            float bb[4] = {bv.x, bv.y, bv.z, bv.w};
#pragma unroll
            for (int i = 0; i < 8; ++i)
#pragma unroll
                for (int j = 0; j < 4; ++j)
                    acc[i][j] += a[i] * bb[j];
        }
        __syncthreads();
    }

    // epilogue: 32-feat chunk-major hs1[(og>>3)*N + node][32] + (og&7)*4
#pragma unroll
    for (int i = 0; i < 8; ++i) {
        int node = nblock + n0 + i;
        if (node < N_NODES) {
            float dv = dinv[node];
            union { __half2 h[2]; float2 f; } u;
            u.h[0] = __floats2half2_rn(acc[i][0] * dv, acc[i][1] * dv);
            u.h[1] = __floats2half2_rn(acc[i][2] * dv, acc[i][3] * dv);
            *(float2*)(hs1 + ((size_t)(og >> 3) * N_NODES + node) * 32 + (og & 7) * 4) = u.f;
        }
    }
}

// ---- aggregate layer 1: 4 XCD-pinned (chunk x src-half) passes -------------
// combo = bid&3 -> XCDs {combo, combo+4}: each XCD gathers from ONE 3.2MB
// sub-table (50000 x 64B) = L2-resident, full-line 64B transactions.
// Half-passes write fp16 partial sums; finalize (dinv/bias/relu) in gemm2.
__global__ __launch_bounds__(256) void k_agg1(const __half* __restrict__ hs1,
                                              const unsigned short* __restrict__ csr,
                                              const int* __restrict__ rowstart,
                                              const int* __restrict__ lens,
                                              __half* __restrict__ out1a,
                                              __half* __restrict__ out1b) {
    int bid = blockIdx.x;            // grid = 25000
    int combo = bid & 3;
    int chunk = combo & 1, half = combo >> 1;
    int nb = bid >> 2;               // 0..6249
    int w = threadIdx.x >> 6, lane = threadIdx.x & 63;
    int slot = lane >> 4, fp = lane & 15;
    int n = nb * 16 + w * 4 + slot;  // 6250*16 = 100000 exact
    const char* T = (const char*)hs1
                  + (size_t)chunk * ((size_t)N_NODES * 64)
                  + (size_t)half * ((size_t)N_HALF * 64);
    unsigned fo = fp * 4u;
    int rs = rowstart[n];
    int L = lens[n];
    int c0 = L & 0xffff;
    int start = half ? (rs + ((c0 + 3) & ~3)) : rs;
    int c = half ? (L >> 16) : c0;
    h2v a0 = {(_Float16)0.f, (_Float16)0.f};
    h2v a1 = a0, a2 = a0, a3 = a0;
    const unsigned long long* Q = (const unsigned long long*)csr;
    int q0 = start >> 2;
    int nq = c >> 2;
    for (int q = 0; q < nq; ++q) {
        unsigned long long e4 = Q[q0 + q];
        a0 += *(const h2v*)(T + (unsigned)(e4 & 0xffffu) * 64u + fo);
        a1 += *(const h2v*)(T + (unsigned)((e4 >> 16) & 0xffffu) * 64u + fo);
        a2 += *(const h2v*)(T + (unsigned)((e4 >> 32) & 0xffffu) * 64u + fo);
        a3 += *(const h2v*)(T + (unsigned)(e4 >> 48) * 64u + fo);
    }
    for (int j = start + (nq << 2); j < start + c; ++j)
        a0 += *(const h2v*)(T + (unsigned)csr[j] * 64u + fo);
    // self-loop contribution in the pass owning n's half
    if ((n >= N_HALF) == (half != 0))
        a1 += *(const h2v*)(T + (unsigned)(n - half * N_HALF) * 64u + fo);
    float sx = ((float)a0.x + (float)a1.x) + ((float)a2.x + (float)a3.x);
    float sy = ((float)a0.y + (float)a1.y) + ((float)a2.y + (float)a3.y);
    h2v o = {(_Float16)sx, (_Float16)sy};
    __half* dst = (half ? out1b : out1a) + (size_t)n * F_HID + chunk * 32 + fp * 2;
    *(h2v*)dst = o;
}

// ---- GEMM2: hs2 = (relu(dinv*(pa+pb)+b1) @ W2) * dinv, fp16 ---------------
__global__ __launch_bounds__(256) void k_gemm2(const __half* __restrict__ out1a,
                                               const __half* __restrict__ out1b,
                                               const float* __restrict__ W2,
                                               const float* __restrict__ dinv,
                                               const float* __restrict__ b1,
                                               __half* __restrict__ hs2) {
    __shared__ float ws[F_HID * F_OUT];
    __shared__ float b1s[F_HID];
    int t = threadIdx.x;
    ((float4*)ws)[t] = ((const float4*)W2)[t];
    if (t < 16) ((float4*)b1s)[t] = ((const float4*)b1)[t];
    __syncthreads();
    int tid = blockIdx.x * 256 + t;
    int n = tid >> 2;
    if (n >= N_NODES) return;
    int cq = (tid & 3) << 2;
    float dv = dinv[n];
    const h2v* A = (const h2v*)(out1a + (size_t)n * F_HID);
    const h2v* B = (const h2v*)(out1b + (size_t)n * F_HID);
    float4 acc = make_float4(0.f, 0.f, 0.f, 0.f);
#pragma unroll 4
    for (int k4 = 0; k4 < 16; ++k4) {
        h2v pa0 = A[k4 * 2], pa1 = A[k4 * 2 + 1];
        h2v pb0 = B[k4 * 2], pb1 = B[k4 * 2 + 1];
        float h0 = fmaxf(dv * ((float)pa0.x + (float)pb0.x) + b1s[k4 * 4 + 0], 0.f);
        float h1 = fmaxf(dv * ((float)pa0.y + (float)pb0.y) + b1s[k4 * 4 + 1], 0.f);
        float h2 = fmaxf(dv * ((float)pa1.x + (float)pb1.x) + b1s[k4 * 4 + 2], 0.f);
        float h3 = fmaxf(dv * ((float)pa1.y + (float)pb1.y) + b1s[k4 * 4 + 3], 0.f);
        float4 w0 = *(const float4*)(ws + (k4 * 4 + 0) * F_OUT + cq);
        float4 w1 = *(const float4*)(ws + (k4 * 4 + 1) * F_OUT + cq);
        float4 w2 = *(const float4*)(ws + (k4 * 4 + 2) * F_OUT + cq);
        float4 w3 = *(const float4*)(ws + (k4 * 4 + 3) * F_OUT + cq);
        acc.x += h0 * w0.x + h1 * w1.x + h2 * w2.x + h3 * w3.x;
        acc.y += h0 * w0.y + h1 * w1.y + h2 * w2.y + h3 * w3.y;
        acc.z += h0 * w0.z + h1 * w1.z + h2 * w2.z + h3 * w3.z;
        acc.w += h0 * w0.w + h1 * w1.w + h2 * w2.w + h3 * w3.w;
    }
    union { __half2 h2x[2]; float2 f; } u;
    u.h2x[0] = __floats2half2_rn(acc.x * dv, acc.y * dv);
    u.h2x[1] = __floats2half2_rn(acc.z * dv, acc.w * dv);
    *(float2*)(hs2 + (size_t)n * F_OUT + cq) = u.f;
}

// ---- aggregate layer 2: single pass (3.2MB table L2-wide), split sub-rows --
__global__ __launch_bounds__(256) void k_agg2(const __half* __restrict__ hs2,
                                              const unsigned short* __restrict__ csr,
                                              const int* __restrict__ rowstart,
                                              const int* __restrict__ lens,
                                              const float* __restrict__ dinv,
                                              const float* __restrict__ b2,
                                              float* __restrict__ out) {
    int w = threadIdx.x >> 6, lane = threadIdx.x & 63;
    int slot = lane >> 3, fp = lane & 7;
    int n = blockIdx.x * 32 + w * 8 + slot;   // grid = 3125
    unsigned fo = fp * 4u;
    int rs = rowstart[n];
    int L = lens[n];
    int c0 = L & 0xffff, c1 = L >> 16;
    const unsigned long long* Q = (const unsigned long long*)csr;
    h2v a0 = {(_Float16)0.f, (_Float16)0.f};
    h2v a1 = a0, a2 = a0, a3 = a0;
#pragma unroll
    for (int half = 0; half < 2; ++half) {
        const char* T = (const char*)hs2 + (size_t)half * ((size_t)N_HALF * 32);
        int start = half ? (rs + ((c0 + 3) & ~3)) : rs;
        int c = half ? c1 : c0;
        int q0 = start >> 2;
        int nq = c >> 2;
        for (int q = 0; q < nq; ++q) {
            unsigned long long e4 = Q[q0 + q];
            a0 += *(const h2v*)(T + (unsigned)(e4 & 0xffffu) * 32u + fo);
            a1 += *(const h2v*)(T + (unsigned)((e4 >> 16) & 0xffffu) * 32u + fo);
            a2 += *(const h2v*)(T + (unsigned)((e4 >> 32) & 0xffffu) * 32u + fo);
            a3 += *(const h2v*)(T + (unsigned)(e4 >> 48) * 32u + fo);
        }
        for (int j = start + (nq << 2); j < start + c; ++j)
            a0 += *(const h2v*)(T + (unsigned)csr[j] * 32u + fo);
    }
    // self
    {
        const char* T = (const char*)hs2;
        a1 += *(const h2v*)(T + (unsigned)n * 32u + fo);
    }
    float dv = dinv[n];
    int fb = fp * 2;
    float sx = ((float)a0.x + (float)a1.x) + ((float)a2.x + (float)a3.x);
    float sy = ((float)a0.y + (float)a1.y) + ((float)a2.y + (float)a3.y);
    float ox = dv * sx + b2[fb];
    float oy = dv * sy + b2[fb + 1];
    *(float2*)(out + (size_t)n * F_OUT + fb) = make_float2(ox, oy);
}

extern "C" void kernel_launch(void* const* d_in, const int* in_sizes, int n_in,
                              void* d_out, int out_size, void* d_ws, size_t ws_size,
                              hipStream_t stream) {
    const float* x  = (const float*)d_in[0];
    const void*  ei = d_in[1];
    const float* W1 = (const float*)d_in[2];
    const float* b1 = (const float*)d_in[3];
    const float* W2 = (const float*)d_in[4];
    const float* b2 = (const float*)d_in[5];
    float* out = (float*)d_out;

    char* ws = (char*)d_ws;
    int*            rowstart = (int*)(ws + OFF_RS);
    int*            lens     = (int*)(ws + OFF_LEN);
    float*          dinv     = (float*)(ws + OFF_DINV);
    int*            gcnt     = (int*)(ws + OFF_GCNT);
    int*            flag     = (int*)(ws + OFF_FLAG);
    unsigned short* csr      = (unsigned short*)(ws + OFF_CSR);
    __half*         hs1      = (__half*)(ws + OFF_HS1);
    __half*         out1a    = (__half*)(ws + OFF_OUT1A);
    __half*         out1b    = (__half*)(ws + OFF_OUT1B);
    __half*         hs2      = (__half*)(ws + OFF_HS2);
    unsigned*       pairs    = (unsigned*)(ws + OFF_PAIRS);

    // edge prep: init + bucket partition + fused count/scan/place (split CSR)
    k_init     <<<1, 512, 0, stream>>>(ei, gcnt, flag);
    k_partition<<<NBLK_P, 256, 0, stream>>>(ei, flag, gcnt, pairs);
    k_build    <<<NBUCK, 512, 0, stream>>>(pairs, gcnt, rowstart, lens, dinv, csr);

    // GCN layers
    k_gemm1<<<G1_BLOCKS, 256, 0, stream>>>(x, W1, dinv, hs1);
    k_agg1 <<<25000, 256, 0, stream>>>(hs1, csr, rowstart, lens, out1a, out1b);
    k_gemm2<<<(N_NODES * 4 + 255) / 256, 256, 0, stream>>>(out1a, out1b, W2, dinv, b1, hs2);
    k_agg2 <<<3125, 256, 0, stream>>>(hs2, csr, rowstart, lens, dinv, b2, out);
}

// Round 14
// 295.208 us; speedup vs baseline: 6.3187x; 1.0494x over previous
//
#include <hip/hip_runtime.h>
#include <hip/hip_fp16.h>
#include <stdint.h>

#define N_NODES   100000
#define N_HALF    50000
#define N_EDGES   3200000
#define F_IN      128
#define F_HID     64
#define F_OUT     16

typedef _Float16 h2v __attribute__((ext_vector_type(2)));

// bucket partition params
#define BSHIFT    8
#define NBUCK     391                  // ceil(100000 / 256)
#define NBLK_P    640                  // partition blocks
#define CHUNK_E   (N_EDGES / NBLK_P)   // 5000 edges per block
#define PSTRIDE   9856                 // bucket capacity: mean padded ~8950 + ~10 sigma

// gemm1 tiling
#define G1_TM     128
#define G1_BLOCKS ((N_NODES + G1_TM - 1) / G1_TM)   // 782
#define XS_LD     132

// ---- workspace layout (bytes), 16B-aligned ----
#define OFF_RS       0                 // int[N]   rowstart (csr entry index, mult of 4)
#define OFF_LEN      400000            // int[N]   c0 | c1<<16 (raw counts per src-half)
#define OFF_DINV     800000            // float[N]
#define OFF_GCNT     1200000           // int[NBUCK]
#define OFF_CSR      1201616           // u16[NBUCK*PSTRIDE] = 7,707,392 B (half-local src)
#define OFF_HS1      8909008           // half[2][N][32] = 12,800,000 B
#define OFF_OUT1A    21709008          // half[N][64] partials (src<50k)
#define OFF_OUT1B    34509008          // half[N][64] partials (src>=50k)
#define OFF_HS2      47309008          // half[N][16]
#define OFF_PAIRS    OFF_OUT1A         // uint[NBUCK*PSTRIDE] = 15.4 MB, aliases out1a/b
// total 50,509,008 bytes

__device__ __forceinline__ int edge_src(const void* ei, int is64, int e) {
    return is64 ? (int)((const long long*)ei)[e] : ((const int*)ei)[e];
}
__device__ __forceinline__ int edge_dst(const void* ei, int is64, int e) {
    return is64 ? (int)((const long long*)ei)[N_EDGES + e]
                : ((const int*)ei)[N_EDGES + e];
}

// ---- pass 1: partition edges into fixed-capacity bucket regions ------------
// Single read of the edge list: (s,d) stashed as u64 in LDS during the
// histogram pass, scattered from LDS afterwards. Dtype detect inlined.
__global__ __launch_bounds__(256) void k_partition(const void* __restrict__ ei,
                                                   int* __restrict__ gcnt,
                                                   unsigned* __restrict__ pairs) {
    __shared__ unsigned long long st[CHUNK_E];   // 40 KB
    __shared__ int h[NBUCK];
    __shared__ int cur[NBUCK];
    __shared__ int is64s;
    int t = threadIdx.x;
    if (t == 0) {
        // int64 data viewed as u32 pairs: [lo<100000, hi==0] x 64. For int32
        // data the hi words are random node ids: P(all zero) ~ 0.
        const unsigned* u = (const unsigned*)ei;
        int ok = 1;
        for (int i = 0; i < 64; ++i) {
            unsigned lo = u[2 * i], hi = u[2 * i + 1];
            if (hi != 0u || lo >= 100000u) { ok = 0; break; }
        }
        is64s = ok;
    }
    for (int i = t; i < NBUCK; i += 256) h[i] = 0;
    __syncthreads();
    int is64 = is64s;
    int base = blockIdx.x * CHUNK_E;
    for (int i = t; i < CHUNK_E; i += 256) {
        int s = edge_src(ei, is64, base + i);
        int d = edge_dst(ei, is64, base + i);
        st[i] = ((unsigned long long)(unsigned)s << 32) | (unsigned)d;
        atomicAdd(&h[d >> BSHIFT], 1);
    }
    __syncthreads();
    for (int i = t; i < NBUCK; i += 256) {
        int c = h[i];
        cur[i] = c ? atomicAdd(&gcnt[i], c) : 0;
    }
    __syncthreads();
    for (int i = t; i < CHUNK_E; i += 256) {
        unsigned long long v = st[i];
        unsigned s = (unsigned)(v >> 32);
        unsigned d = (unsigned)v;
        int b = d >> BSHIFT;
        int p = atomicAdd(&cur[b], 1);
        if (p < PSTRIDE)   // statistically impossible to overflow; guard anyway
            pairs[b * PSTRIDE + p] = (s << 8) | (d & 255u);
    }
}

// ---- pass 2: per-bucket count/scan/place, split by src-half ----------------
// Per node: sub-row 0 (src<50000) then sub-row 1, each start 4-entry aligned.
// Entries are u16 half-local src. No padding writes (raw counts stored).
__global__ __launch_bounds__(512) void k_build(const unsigned* __restrict__ pairs,
                                               const int* __restrict__ gcnt,
                                               int* __restrict__ rowstart,
                                               int* __restrict__ lens,
                                               float* __restrict__ dinv,
                                               unsigned short* __restrict__ csr) {
    __shared__ int c0S[256], c1S[256], scanS[256], pos0[256], pos1[256];
    int b = blockIdx.x, t = threadIdx.x;
    if (t < 256) { c0S[t] = 0; c1S[t] = 0; }
    __syncthreads();
    int tot = gcnt[b]; if (tot > PSTRIDE) tot = PSTRIDE;
    int base = b * PSTRIDE;
    for (int i = t; i < tot; i += 512) {
        unsigned pr = pairs[base + i];
        if ((pr >> 8) < (unsigned)N_HALF) atomicAdd(&c0S[pr & 255u], 1);
        else                              atomicAdd(&c1S[pr & 255u], 1);
    }
    __syncthreads();
    int tpad = 0, p0a = 0;
    if (t < 256) {
        p0a = (c0S[t] + 3) & ~3;
        tpad = p0a + ((c1S[t] + 3) & ~3);
        scanS[t] = tpad;
    }
    __syncthreads();
    for (int off = 1; off < 256; off <<= 1) {
        int add = 0;
        if (t < 256 && t >= off) add = scanS[t - off];
        __syncthreads();
        if (t < 256) scanS[t] += add;
        __syncthreads();
    }
    if (t < 256) {
        int rs = base + scanS[t] - tpad;   // exclusive scan, 4-entry aligned
        pos0[t] = rs;
        pos1[t] = rs + p0a;
        int d = (b << BSHIFT) + t;
        if (d < N_NODES) {
            rowstart[d] = rs;
            lens[d] = c0S[t] | (c1S[t] << 16);
            dinv[d] = rsqrtf((float)(c0S[t] + c1S[t]) + 1.0f);
        }
    }
    __syncthreads();
    for (int i = t; i < tot; i += 512) {
        unsigned pr = pairs[base + i];
        unsigned s = pr >> 8;
        int d = pr & 255u;
        if (s < (unsigned)N_HALF) {
            int p = atomicAdd(&pos0[d], 1);
            csr[p] = (unsigned short)s;
        } else {
            int p = atomicAdd(&pos1[d], 1);
            csr[p] = (unsigned short)(s - N_HALF);
        }
    }
}

// ---- GEMM1 (LDS-tiled): hs1[chunk32][node][32] = (x@W1)*dinv ---------------
__global__ __launch_bounds__(256) void k_gemm1(const float* __restrict__ x,
                                               const float* __restrict__ W1,
                                               const float* __restrict__ dinv,
                                               __half* __restrict__ hs1) {
    __shared__ float xsT[64 * XS_LD];
    __shared__ float ws[64 * 64];
    int t = threadIdx.x;
    int nblock = blockIdx.x * G1_TM;
    int ng = t >> 4, og = t & 15;
    int n0 = ng * 8;
    float acc[8][4] = {};

    int snode = nblock + (t >> 1);
    int koff = (t & 1) * 32;
    int nl = t >> 1;

    for (int chunk = 0; chunk < 2; ++chunk) {
        int kbase = chunk * 64;
        {
            float4 v[8];
            if (snode < N_NODES) {
                const float4* src = (const float4*)(x + (size_t)snode * F_IN + kbase + koff);
#pragma unroll
                for (int c = 0; c < 8; ++c) v[c] = src[c];
            } else {
#pragma unroll
                for (int c = 0; c < 8; ++c) v[c] = make_float4(0.f, 0.f, 0.f, 0.f);
            }
#pragma unroll
            for (int c = 0; c < 8; ++c) {
                int k = koff + c * 4;
                xsT[(k + 0) * XS_LD + nl] = v[c].x;
                xsT[(k + 1) * XS_LD + nl] = v[c].y;
                xsT[(k + 2) * XS_LD + nl] = v[c].z;
                xsT[(k + 3) * XS_LD + nl] = v[c].w;
            }
        }
        {
            const float4* wsrc = (const float4*)(W1 + kbase * F_HID);
            float4* wdst = (float4*)ws;
#pragma unroll
            for (int c = 0; c < 4; ++c) wdst[c * 256 + t] = wsrc[c * 256 + t];
        }
        __syncthreads();

#pragma unroll 4
        for (int k = 0; k < 64; ++k) {
            const float4* xr = (const float4*)(xsT + k * XS_LD + n0);
            float4 a0 = xr[0], a1 = xr[1];
            float4 bv = *(const float4*)(ws + k * 64 + og * 4);
            float a[8] = {a0.x, a0.y, a0.z, a0.w, a1.x, a1.y, a1.z, a1.w};
            float bb[4] = {bv.x, bv.y, bv.z, bv.w};
#pragma unroll
            for (int i = 0; i < 8; ++i)
#pragma unroll
                for (int j = 0; j < 4; ++j)
                    acc[i][j] += a[i] * bb[j];
        }
        __syncthreads();
    }

    // epilogue: 32-feat chunk-major hs1[(og>>3)*N + node][32] + (og&7)*4
#pragma unroll
    for (int i = 0; i < 8; ++i) {
        int node = nblock + n0 + i;
        if (node < N_NODES) {
            float dv = dinv[node];
            union { __half2 h[2]; float2 f; } u;
            u.h[0] = __floats2half2_rn(acc[i][0] * dv, acc[i][1] * dv);
            u.h[1] = __floats2half2_rn(acc[i][2] * dv, acc[i][3] * dv);
            *(float2*)(hs1 + ((size_t)(og >> 3) * N_NODES + node) * 32 + (og & 7) * 4) = u.f;
        }
    }
}

// ---- aggregate layer 1: 4 XCD-pinned (chunk x src-half) passes -------------
// combo = bid&3 -> XCDs {combo, combo+4}: each XCD gathers from ONE 3.2MB
// sub-table (50000 x 64B) = L2-resident, full-line 64B transactions.
// Half-passes write fp16 partial sums; finalize (dinv/bias/relu) in gemm2.
// Unroll-2: 8 gathers in flight per iter.
__global__ __launch_bounds__(256) void k_agg1(const __half* __restrict__ hs1,
                                              const unsigned short* __restrict__ csr,
                                              const int* __restrict__ rowstart,
                                              const int* __restrict__ lens,
                                              __half* __restrict__ out1a,
                                              __half* __restrict__ out1b) {
    int bid = blockIdx.x;            // grid = 25000
    int combo = bid & 3;
    int chunk = combo & 1, half = combo >> 1;
    int nb = bid >> 2;               // 0..6249
    int w = threadIdx.x >> 6, lane = threadIdx.x & 63;
    int slot = lane >> 4, fp = lane & 15;
    int n = nb * 16 + w * 4 + slot;  // 6250*16 = 100000 exact
    const char* T = (const char*)hs1
                  + (size_t)chunk * ((size_t)N_NODES * 64)
                  + (size_t)half * ((size_t)N_HALF * 64);
    unsigned fo = fp * 4u;
    int rs = rowstart[n];
    int L = lens[n];
    int c0 = L & 0xffff;
    int start = half ? (rs + ((c0 + 3) & ~3)) : rs;
    int c = half ? (L >> 16) : c0;
    h2v a0 = {(_Float16)0.f, (_Float16)0.f};
    h2v a1 = a0, a2 = a0, a3 = a0;
    const unsigned long long* Q = (const unsigned long long*)csr;
    int q0 = start >> 2;
    int nq = c >> 2;
    int q = 0;
    for (; q + 2 <= nq; q += 2) {
        unsigned long long ea = Q[q0 + q], eb = Q[q0 + q + 1];
        a0 += *(const h2v*)(T + (unsigned)(ea & 0xffffu) * 64u + fo);
        a1 += *(const h2v*)(T + (unsigned)((ea >> 16) & 0xffffu) * 64u + fo);
        a2 += *(const h2v*)(T + (unsigned)((ea >> 32) & 0xffffu) * 64u + fo);
        a3 += *(const h2v*)(T + (unsigned)(ea >> 48) * 64u + fo);
        a0 += *(const h2v*)(T + (unsigned)(eb & 0xffffu) * 64u + fo);
        a1 += *(const h2v*)(T + (unsigned)((eb >> 16) & 0xffffu) * 64u + fo);
        a2 += *(const h2v*)(T + (unsigned)((eb >> 32) & 0xffffu) * 64u + fo);
        a3 += *(const h2v*)(T + (unsigned)(eb >> 48) * 64u + fo);
    }
    if (q < nq) {
        unsigned long long ea = Q[q0 + q];
        a0 += *(const h2v*)(T + (unsigned)(ea & 0xffffu) * 64u + fo);
        a1 += *(const h2v*)(T + (unsigned)((ea >> 16) & 0xffffu) * 64u + fo);
        a2 += *(const h2v*)(T + (unsigned)((ea >> 32) & 0xffffu) * 64u + fo);
        a3 += *(const h2v*)(T + (unsigned)(ea >> 48) * 64u + fo);
    }
    for (int j = start + (nq << 2); j < start + c; ++j)
        a0 += *(const h2v*)(T + (unsigned)csr[j] * 64u + fo);
    // self-loop contribution in the pass owning n's half
    if ((n >= N_HALF) == (half != 0))
        a1 += *(const h2v*)(T + (unsigned)(n - half * N_HALF) * 64u + fo);
    float sx = ((float)a0.x + (float)a1.x) + ((float)a2.x + (float)a3.x);
    float sy = ((float)a0.y + (float)a1.y) + ((float)a2.y + (float)a3.y);
    h2v o = {(_Float16)sx, (_Float16)sy};
    __half* dst = (half ? out1b : out1a) + (size_t)n * F_HID + chunk * 32 + fp * 2;
    *(h2v*)dst = o;
}

// ---- GEMM2: hs2 = (relu(dinv*(pa+pb)+b1) @ W2) * dinv, fp16 ---------------
__global__ __launch_bounds__(256) void k_gemm2(const __half* __restrict__ out1a,
                                               const __half* __restrict__ out1b,
                                               const float* __restrict__ W2,
                                               const float* __restrict__ dinv,
                                               const float* __restrict__ b1,
                                               __half* __restrict__ hs2) {
    __shared__ float ws[F_HID * F_OUT];
    __shared__ float b1s[F_HID];
    int t = threadIdx.x;
    ((float4*)ws)[t] = ((const float4*)W2)[t];
    if (t < 16) ((float4*)b1s)[t] = ((const float4*)b1)[t];
    __syncthreads();
    int tid = blockIdx.x * 256 + t;
    int n = tid >> 2;
    if (n >= N_NODES) return;
    int cq = (tid & 3) << 2;
    float dv = dinv[n];
    const h2v* A = (const h2v*)(out1a + (size_t)n * F_HID);
    const h2v* B = (const h2v*)(out1b + (size_t)n * F_HID);
    float4 acc = make_float4(0.f, 0.f, 0.f, 0.f);
#pragma unroll 4
    for (int k4 = 0; k4 < 16; ++k4) {
        h2v pa0 = A[k4 * 2], pa1 = A[k4 * 2 + 1];
        h2v pb0 = B[k4 * 2], pb1 = B[k4 * 2 + 1];
        float h0 = fmaxf(dv * ((float)pa0.x + (float)pb0.x) + b1s[k4 * 4 + 0], 0.f);
        float h1 = fmaxf(dv * ((float)pa0.y + (float)pb0.y) + b1s[k4 * 4 + 1], 0.f);
        float h2 = fmaxf(dv * ((float)pa1.x + (float)pb1.x) + b1s[k4 * 4 + 2], 0.f);
        float h3 = fmaxf(dv * ((float)pa1.y + (float)pb1.y) + b1s[k4 * 4 + 3], 0.f);
        float4 w0 = *(const float4*)(ws + (k4 * 4 + 0) * F_OUT + cq);
        float4 w1 = *(const float4*)(ws + (k4 * 4 + 1) * F_OUT + cq);
        float4 w2 = *(const float4*)(ws + (k4 * 4 + 2) * F_OUT + cq);
        float4 w3 = *(const float4*)(ws + (k4 * 4 + 3) * F_OUT + cq);
        acc.x += h0 * w0.x + h1 * w1.x + h2 * w2.x + h3 * w3.x;
        acc.y += h0 * w0.y + h1 * w1.y + h2 * w2.y + h3 * w3.y;
        acc.z += h0 * w0.z + h1 * w1.z + h2 * w2.z + h3 * w3.z;
        acc.w += h0 * w0.w + h1 * w1.w + h2 * w2.w + h3 * w3.w;
    }
    union { __half2 h2x[2]; float2 f; } u;
    u.h2x[0] = __floats2half2_rn(acc.x * dv, acc.y * dv);
    u.h2x[1] = __floats2half2_rn(acc.z * dv, acc.w * dv);
    *(float2*)(hs2 + (size_t)n * F_OUT + cq) = u.f;
}

// ---- aggregate layer 2: single pass (3.2MB table L2-wide), split sub-rows --
__global__ __launch_bounds__(256) void k_agg2(const __half* __restrict__ hs2,
                                              const unsigned short* __restrict__ csr,
                                              const int* __restrict__ rowstart,
                                              const int* __restrict__ lens,
                                              const float* __restrict__ dinv,
                                              const float* __restrict__ b2,
                                              float* __restrict__ out) {
    int w = threadIdx.x >> 6, lane = threadIdx.x & 63;
    int slot = lane >> 3, fp = lane & 7;
    int n = blockIdx.x * 32 + w * 8 + slot;   // grid = 3125
    unsigned fo = fp * 4u;
    int rs = rowstart[n];
    int L = lens[n];
    int c0 = L & 0xffff, c1 = L >> 16;
    const unsigned long long* Q = (const unsigned long long*)csr;
    h2v a0 = {(_Float16)0.f, (_Float16)0.f};
    h2v a1 = a0, a2 = a0, a3 = a0;
#pragma unroll
    for (int half = 0; half < 2; ++half) {
        const char* T = (const char*)hs2 + (size_t)half * ((size_t)N_HALF * 32);
        int start = half ? (rs + ((c0 + 3) & ~3)) : rs;
        int c = half ? c1 : c0;
        int q0 = start >> 2;
        int nq = c >> 2;
        int q = 0;
        for (; q + 2 <= nq; q += 2) {
            unsigned long long ea = Q[q0 + q], eb = Q[q0 + q + 1];
            a0 += *(const h2v*)(T + (unsigned)(ea & 0xffffu) * 32u + fo);
            a1 += *(const h2v*)(T + (unsigned)((ea >> 16) & 0xffffu) * 32u + fo);
            a2 += *(const h2v*)(T + (unsigned)((ea >> 32) & 0xffffu) * 32u + fo);
            a3 += *(const h2v*)(T + (unsigned)(ea >> 48) * 32u + fo);
            a0 += *(const h2v*)(T + (unsigned)(eb & 0xffffu) * 32u + fo);
            a1 += *(const h2v*)(T + (unsigned)((eb >> 16) & 0xffffu) * 32u + fo);
            a2 += *(const h2v*)(T + (unsigned)((eb >> 32) & 0xffffu) * 32u + fo);
            a3 += *(const h2v*)(T + (unsigned)(eb >> 48) * 32u + fo);
        }
        if (q < nq) {
            unsigned long long ea = Q[q0 + q];
            a0 += *(const h2v*)(T + (unsigned)(ea & 0xffffu) * 32u + fo);
            a1 += *(const h2v*)(T + (unsigned)((ea >> 16) & 0xffffu) * 32u + fo);
            a2 += *(const h2v*)(T + (unsigned)((ea >> 32) & 0xffffu) * 32u + fo);
            a3 += *(const h2v*)(T + (unsigned)(ea >> 48) * 32u + fo);
        }
        for (int j = start + (nq << 2); j < start + c; ++j)
            a0 += *(const h2v*)(T + (unsigned)csr[j] * 32u + fo);
    }
    // self
    a1 += *(const h2v*)((const char*)hs2 + (unsigned)n * 32u + fo);
    float dv = dinv[n];
    int fb = fp * 2;
    float sx = ((float)a0.x + (float)a1.x) + ((float)a2.x + (float)a3.x);
    float sy = ((float)a0.y + (float)a1.y) + ((float)a2.y + (float)a3.y);
    float ox = dv * sx + b2[fb];
    float oy = dv * sy + b2[fb + 1];
    *(float2*)(out + (size_t)n * F_OUT + fb) = make_float2(ox, oy);
}

extern "C" void kernel_launch(void* const* d_in, const int* in_sizes, int n_in,
                              void* d_out, int out_size, void* d_ws, size_t ws_size,
                              hipStream_t stream) {
    const float* x  = (const float*)d_in[0];
    const void*  ei = d_in[1];
    const float* W1 = (const float*)d_in[2];
    const float* b1 = (const float*)d_in[3];
    const float* W2 = (const float*)d_in[4];
    const float* b2 = (const float*)d_in[5];
    float* out = (float*)d_out;

    char* ws = (char*)d_ws;
    int*            rowstart = (int*)(ws + OFF_RS);
    int*            lens     = (int*)(ws + OFF_LEN);
    float*          dinv     = (float*)(ws + OFF_DINV);
    int*            gcnt     = (int*)(ws + OFF_GCNT);
    unsigned short* csr      = (unsigned short*)(ws + OFF_CSR);
    __half*         hs1      = (__half*)(ws + OFF_HS1);
    __half*         out1a    = (__half*)(ws + OFF_OUT1A);
    __half*         out1b    = (__half*)(ws + OFF_OUT1B);
    __half*         hs2      = (__half*)(ws + OFF_HS2);
    unsigned*       pairs    = (unsigned*)(ws + OFF_PAIRS);

    // edge prep: bucket partition (single edge read) + fused count/scan/place
    hipMemsetAsync(gcnt, 0, NBUCK * sizeof(int), stream);
    k_partition<<<NBLK_P, 256, 0, stream>>>(ei, gcnt, pairs);
    k_build    <<<NBUCK, 512, 0, stream>>>(pairs, gcnt, rowstart, lens, dinv, csr);

    // GCN layers
    k_gemm1<<<G1_BLOCKS, 256, 0, stream>>>(x, W1, dinv, hs1);
    k_agg1 <<<25000, 256, 0, stream>>>(hs1, csr, rowstart, lens, out1a, out1b);
    k_gemm2<<<(N_NODES * 4 + 255) / 256, 256, 0, stream>>>(out1a, out1b, W2, dinv, b1, hs2);
    k_agg2 <<<3125, 256, 0, stream>>>(hs2, csr, rowstart, lens, dinv, b2, out);
}